// Round 1
// baseline (697.293 us; speedup 1.0000x reference)
//
#include <hip/hip_runtime.h>
#include <hip/hip_bf16.h>
#include <math.h>

#define BB 64
#define NN 128
#define DD 32
#define PP (NN * (NN - 1))   // 16256
#define H1W 32
#define H2W 32
#define HFW 16
#define EPSF 1e-5f
#define SLOPEF 0.01f

static __device__ __forceinline__ float leaky(float x) {
    return (x >= 0.f) ? x : SLOPEF * x;
}

// Kernel 1: per-edge-index stats over (B, H1) of h = paired @ W1 + b1.
// One block per p. 256 threads: thread = (b_base = tid>>5, j = tid&31), 8 b's each.
__global__ __launch_bounds__(256) void stats_kernel(
    const float* __restrict__ inputs, const int* __restrict__ tgt,
    const float* __restrict__ W1, const float* __restrict__ b1,
    const float* __restrict__ g1, const float* __restrict__ be1,
    float* __restrict__ statA, float* __restrict__ statB)
{
    __shared__ float W1s[64][32];
    __shared__ float Xs[64][64];
    __shared__ float b1s[32];
    __shared__ float rs[4], rq[4];

    int p = blockIdx.x;
    int tid = threadIdx.x;
    int s = p / (NN - 1);
    int tn = tgt[p];

    for (int idx = tid; idx < 2048; idx += 256)
        W1s[idx >> 5][idx & 31] = W1[idx];
    if (tid < 32) b1s[tid] = b1[tid];

    const float* srcp = inputs + (size_t)s * DD;
    const float* tgtp = inputs + (size_t)tn * DD;
    for (int idx = tid; idx < 2048; idx += 256) {
        int b = idx >> 5, d = idx & 31;
        Xs[b][d]      = srcp[(size_t)b * (NN * DD) + d];
        Xs[b][32 + d] = tgtp[(size_t)b * (NN * DD) + d];
    }
    __syncthreads();

    int j = tid & 31;
    int bb = tid >> 5;
    float sum = 0.f, ss = 0.f;
    for (int it = 0; it < 8; ++it) {
        int b = bb + it * 8;
        float acc = b1s[j];
        #pragma unroll
        for (int k = 0; k < 64; ++k) acc += Xs[b][k] * W1s[k][j];
        sum += acc;
        ss += acc * acc;
    }
    // wave (64-lane) reduce, then cross-wave via LDS
    #pragma unroll
    for (int off = 32; off > 0; off >>= 1) {
        sum += __shfl_down(sum, off, 64);
        ss  += __shfl_down(ss, off, 64);
    }
    int wave = tid >> 6;
    int lane = tid & 63;
    if (lane == 0) { rs[wave] = sum; rq[wave] = ss; }
    __syncthreads();
    if (tid == 0) {
        float S = rs[0] + rs[1] + rs[2] + rs[3];
        float Q = rq[0] + rq[1] + rq[2] + rq[3];
        float mean = S * (1.f / 2048.f);
        float var  = Q * (1.f / 2048.f) - mean * mean;
        float inv  = rsqrtf(var + EPSF);
        float sc   = inv * g1[p];
        statA[p] = sc;
        statB[p] = be1[p] - mean * sc;
    }
}

// Kernel 2: per (src node i, batch-slice of 8). Recompute h, norm+leaky, @W2,
// leaky, @W3; sigmoid col0 -> edges out; register-accumulate weighted messages
// over the 127 edges of src i -> agg (exclusive writes, no atomics).
__global__ __launch_bounds__(256) void edges_kernel(
    const float* __restrict__ inputs, const int* __restrict__ tgt,
    const float* __restrict__ W1, const float* __restrict__ b1,
    const float* __restrict__ W2, const float* __restrict__ b2,
    const float* __restrict__ W3, const float* __restrict__ b3,
    const float* __restrict__ statA, const float* __restrict__ statB,
    float* __restrict__ edges_out, float* __restrict__ agg)
{
    __shared__ float W1s[64][32];
    __shared__ float W2s[32][32];
    __shared__ float W3s[32][33];
    __shared__ float b1s[32], b2s[32], b3s[33];
    __shared__ float Xsrc[8][32], Xtgt[8][32];
    __shared__ float Hs[8][32];
    __shared__ float H2s[8][32];
    __shared__ float Ms[8][32];
    __shared__ float ev[8];

    int bx = blockIdx.x;
    int i  = bx >> 3;          // src node
    int b0 = (bx & 7) * 8;     // batch slice start
    int tid = threadIdx.x;
    int bl = tid >> 5, d = tid & 31;

    for (int idx = tid; idx < 2048; idx += 256) W1s[idx >> 5][idx & 31] = W1[idx];
    for (int idx = tid; idx < 1024; idx += 256) W2s[idx >> 5][idx & 31] = W2[idx];
    for (int idx = tid; idx < 1056; idx += 256) W3s[idx / 33][idx % 33] = W3[idx];
    if (tid < 32) { b1s[tid] = b1[tid]; b2s[tid] = b2[tid]; }
    if (tid < 33) b3s[tid] = b3[tid];

    Xsrc[bl][d] = inputs[(size_t)(b0 + bl) * (NN * DD) + (size_t)i * DD + d];

    float aggacc = 0.f;
    for (int e = 0; e < NN - 1; ++e) {
        int p = i * (NN - 1) + e;
        int tn = tgt[p];
        __syncthreads();   // protect Ms/ev reads of prev iter before rewrites
        Xtgt[bl][d] = inputs[(size_t)(b0 + bl) * (NN * DD) + (size_t)tn * DD + d];
        float sc = statA[p], sh = statB[p];
        __syncthreads();

        // h = paired @ W1 + b1, normalized + leaky
        float acc = b1s[d];
        #pragma unroll
        for (int k = 0; k < 32; ++k) acc += Xsrc[bl][k] * W1s[k][d];
        #pragma unroll
        for (int k = 0; k < 32; ++k) acc += Xtgt[bl][k] * W1s[32 + k][d];
        acc = acc * sc + sh;
        Hs[bl][d] = leaky(acc);
        __syncthreads();

        // h2 = leaky(h @ W2 + b2)
        acc = b2s[d];
        #pragma unroll
        for (int k = 0; k < 32; ++k) acc += Hs[bl][k] * W2s[k][d];
        H2s[bl][d] = leaky(acc);
        __syncthreads();

        // out3 = h2 @ W3 + b3 (33 cols): col0 -> sigmoid edge, cols1.. -> message
        for (int idx = tid; idx < 264; idx += 256) {
            int rb = idx / 33, c = idx % 33;
            float a2 = b3s[c];
            #pragma unroll
            for (int k = 0; k < 32; ++k) a2 += H2s[rb][k] * W3s[k][c];
            if (c == 0) {
                float evv = 1.f / (1.f + expf(-a2));
                ev[rb] = evv;
                edges_out[(size_t)(b0 + rb) * PP + p] = evv;
            } else {
                Ms[rb][c - 1] = a2;
            }
        }
        __syncthreads();
        aggacc += ev[bl] * Ms[bl][d];
    }
    agg[(size_t)(b0 + bl) * (NN * DD) + (size_t)i * DD + d] = aggacc;
}

// Kernel 3a: f = [inputs, agg] @ Wf1 + bf1 per row; block-reduce per-feature
// sum/sumsq, one atomicAdd per feature per block.
__global__ __launch_bounds__(256) void f_kernel(
    const float* __restrict__ inputs, const float* __restrict__ agg,
    const float* __restrict__ Wf1, const float* __restrict__ bf1,
    float* __restrict__ f, float* __restrict__ fsum, float* __restrict__ fss)
{
    __shared__ float Wf1s[64][16];
    __shared__ float Xs[16][64];
    __shared__ float rsum[256], rss[256];

    int tid = threadIdx.x;
    int row0 = blockIdx.x * 16;
    for (int idx = tid; idx < 1024; idx += 256)
        Wf1s[idx >> 4][idx & 15] = Wf1[idx];
    for (int idx = tid; idx < 512; idx += 256) {
        int r = idx >> 5, d = idx & 31;
        Xs[r][d]      = inputs[(size_t)(row0 + r) * 32 + d];
        Xs[r][32 + d] = agg[(size_t)(row0 + r) * 32 + d];
    }
    __syncthreads();

    int rl = tid >> 4, j = tid & 15;
    float acc = bf1[j];
    #pragma unroll
    for (int k = 0; k < 64; ++k) acc += Xs[rl][k] * Wf1s[k][j];
    f[(size_t)(row0 + rl) * 16 + j] = acc;

    rsum[tid] = acc;
    rss[tid]  = acc * acc;
    __syncthreads();
    for (int s = 128; s >= 16; s >>= 1) {
        if (tid < s) { rsum[tid] += rsum[tid + s]; rss[tid] += rss[tid + s]; }
        __syncthreads();
    }
    if (tid < 16) {
        atomicAdd(&fsum[tid], rsum[tid]);
        atomicAdd(&fss[tid],  rss[tid]);
    }
}

// Kernel 3b: normalize f per-feature, leaky, @ Wf2 + bf2 -> out.
__global__ __launch_bounds__(256) void out_kernel(
    const float* __restrict__ f, const float* __restrict__ fsum,
    const float* __restrict__ fss,
    const float* __restrict__ gf, const float* __restrict__ bef,
    const float* __restrict__ Wf2, const float* __restrict__ bf2,
    float* __restrict__ outp)
{
    __shared__ float Wf2s[16][32];
    __shared__ float sc[16], sh[16];
    __shared__ float fs[8][16];

    int tid = threadIdx.x;
    for (int idx = tid; idx < 512; idx += 256)
        Wf2s[idx >> 5][idx & 31] = Wf2[idx];
    if (tid < 16) {
        float mean = fsum[tid] * (1.f / 8192.f);
        float var  = fss[tid] * (1.f / 8192.f) - mean * mean;
        float inv  = rsqrtf(var + EPSF);
        float s    = inv * gf[tid];
        sc[tid] = s;
        sh[tid] = bef[tid] - mean * s;
    }
    int row0 = blockIdx.x * 8;
    if (tid < 128) {
        int r = tid >> 4, j = tid & 15;
        fs[r][j] = f[(size_t)(row0 + r) * 16 + j];
    }
    __syncthreads();

    int rl = tid >> 5, d = tid & 31;
    float acc = bf2[d];
    #pragma unroll
    for (int j = 0; j < 16; ++j) {
        float v = fs[rl][j] * sc[j] + sh[j];
        v = leaky(v);
        acc += v * Wf2s[j][d];
    }
    outp[(size_t)(row0 + rl) * 32 + d] = acc;
}

extern "C" void kernel_launch(void* const* d_in, const int* in_sizes, int n_in,
                              void* d_out, int out_size, void* d_ws, size_t ws_size,
                              hipStream_t stream) {
    const float* inputs = (const float*)d_in[0];
    // d_in[1] = src (implicit: p / 127), unused
    const int*   tgt  = (const int*)d_in[2];
    const float* W1   = (const float*)d_in[3];
    const float* b1   = (const float*)d_in[4];
    const float* g1   = (const float*)d_in[5];
    const float* be1  = (const float*)d_in[6];
    const float* W2   = (const float*)d_in[7];
    const float* b2   = (const float*)d_in[8];
    const float* W3   = (const float*)d_in[9];
    const float* b3   = (const float*)d_in[10];
    const float* Wf1  = (const float*)d_in[11];
    const float* bf1  = (const float*)d_in[12];
    const float* gf   = (const float*)d_in[13];
    const float* bef  = (const float*)d_in[14];
    const float* Wf2  = (const float*)d_in[15];
    const float* bf2  = (const float*)d_in[16];

    float* ws    = (float*)d_ws;
    float* statA = ws;                       // P
    float* statB = statA + PP;               // P
    float* agg   = statB + PP;               // B*N*D = 262144
    float* f     = agg + (size_t)BB * NN * DD; // 8192*16
    float* fsum  = f + 8192 * 16;            // 16
    float* fss   = fsum + 16;                // 16

    float* edges_out = (float*)d_out;                    // B*P
    float* outp      = edges_out + (size_t)BB * PP;      // B*N*D

    hipMemsetAsync(fsum, 0, 2 * 16 * sizeof(float), stream);

    stats_kernel<<<PP, 256, 0, stream>>>(inputs, tgt, W1, b1, g1, be1, statA, statB);
    edges_kernel<<<NN * 8, 256, 0, stream>>>(inputs, tgt, W1, b1, W2, b2, W3, b3,
                                             statA, statB, edges_out, agg);
    f_kernel<<<8192 / 16, 256, 0, stream>>>(inputs, agg, Wf1, bf1, f, fsum, fss);
    out_kernel<<<8192 / 8, 256, 0, stream>>>(f, fsum, fss, gf, bef, Wf2, bf2, outp);
}

// Round 2
// 378.737 us; speedup vs baseline: 1.8411x; 1.8411x over previous
//
#include <hip/hip_runtime.h>
#include <hip/hip_bf16.h>
#include <math.h>

#define BB 64
#define NN 128
#define DD 32
#define PP (NN * (NN - 1))   // 16256
#define EPSF 1e-5f

// ws layout (floats):
// AT [128 nodes][64 b][32 j]  = 262144   (A' = x@W1_top + b1, transposed node-major)
// BT [128][64][32]            = 262144   (Bm = x@W1_bot)
// SA[128] QA[128] SB[128] QB[128]
// statA[P] statB[P]
// agg [b][n][32]              = 262144
// f   [8192][16]              = 131072
// fsum[16] fss[16]

// ---------------- Kernel A: per-node projections ----------------
// grid 128 blocks x 256 thr; block handles 64 rows (row = b*128+n).
__global__ __launch_bounds__(256) void proj_kernel(
    const float* __restrict__ inputs, const float* __restrict__ W1,
    const float* __restrict__ b1,
    float* __restrict__ AT, float* __restrict__ BT)
{
    __shared__ float Xs[64][32];
    int tid = threadIdx.x;
    int j = tid & 31, rblk = tid >> 5;
    int row0 = blockIdx.x * 64;

    for (int idx = tid; idx < 2048; idx += 256)
        Xs[idx >> 5][idx & 31] = inputs[(size_t)row0 * 32 + idx];

    float wa[32], wb[32];
    #pragma unroll
    for (int k = 0; k < 32; ++k) {
        wa[k] = W1[k * 32 + j];
        wb[k] = W1[(k + 32) * 32 + j];
    }
    float b1j = b1[j];
    __syncthreads();

    #pragma unroll
    for (int i = 0; i < 8; ++i) {
        int r = rblk * 8 + i;
        float a = b1j, c = 0.f;
        #pragma unroll
        for (int k = 0; k < 32; ++k) {
            a += Xs[r][k] * wa[k];
            c += Xs[r][k] * wb[k];
        }
        int row = row0 + r;
        int n = row & 127, b = row >> 7;
        AT[((size_t)n * 64 + b) * 32 + j] = a;
        BT[((size_t)n * 64 + b) * 32 + j] = c;
    }
}

// ---------------- Kernel A2: per-node sums over (b,j) ----------------
// grid 128 blocks (n) x 256 thr.
__global__ __launch_bounds__(256) void sums_kernel(
    const float* __restrict__ AT, const float* __restrict__ BT,
    float* __restrict__ SA, float* __restrict__ QA,
    float* __restrict__ SB, float* __restrict__ QB)
{
    __shared__ float red[4][4];
    int n = blockIdx.x, tid = threadIdx.x;
    float sa = 0.f, qa = 0.f, sb = 0.f, qb = 0.f;
    #pragma unroll
    for (int it = 0; it < 8; ++it) {
        int m = tid + it * 256;
        float a = AT[(size_t)n * 2048 + m];
        float c = BT[(size_t)n * 2048 + m];
        sa += a; qa += a * a; sb += c; qb += c * c;
    }
    #pragma unroll
    for (int off = 32; off > 0; off >>= 1) {
        sa += __shfl_down(sa, off, 64);
        qa += __shfl_down(qa, off, 64);
        sb += __shfl_down(sb, off, 64);
        qb += __shfl_down(qb, off, 64);
    }
    int w = tid >> 6;
    if ((tid & 63) == 0) { red[w][0] = sa; red[w][1] = qa; red[w][2] = sb; red[w][3] = qb; }
    __syncthreads();
    if (tid == 0) {
        SA[n] = red[0][0] + red[1][0] + red[2][0] + red[3][0];
        QA[n] = red[0][1] + red[1][1] + red[2][1] + red[3][1];
        SB[n] = red[0][2] + red[1][2] + red[2][2] + red[3][2];
        QB[n] = red[0][3] + red[1][3] + red[2][3] + red[3][3];
    }
}

// ---------------- Kernel B: per-edge LN stats via cross-dot ----------------
// grid 128 blocks (s) x 256 thr (4 waves; wave handles edges e = w, w+4, ...)
__global__ __launch_bounds__(256) void stats_kernel(
    const float* __restrict__ AT, const float* __restrict__ BT,
    const float* __restrict__ SA, const float* __restrict__ QA,
    const float* __restrict__ SB, const float* __restrict__ QB,
    const int* __restrict__ tgt,
    const float* __restrict__ g1, const float* __restrict__ be1,
    float* __restrict__ statA, float* __restrict__ statB)
{
    __shared__ float As[2048];
    int s = blockIdx.x, tid = threadIdx.x;
    for (int idx = tid; idx < 2048; idx += 256)
        As[idx] = AT[(size_t)s * 2048 + idx];
    __syncthreads();

    int w = tid >> 6, lane = tid & 63;
    float sa_s = SA[s], qa_s = QA[s];
    for (int e = w; e < 127; e += 4) {
        int p = s * 127 + e;
        int t = tgt[p];
        const float4* bt4 = (const float4*)(BT + (size_t)t * 2048);
        const float4* as4 = (const float4*)As;
        float dot = 0.f;
        #pragma unroll
        for (int it = 0; it < 8; ++it) {
            float4 bv = bt4[lane + it * 64];
            float4 av = as4[lane + it * 64];
            dot += av.x * bv.x + av.y * bv.y + av.z * bv.z + av.w * bv.w;
        }
        #pragma unroll
        for (int m = 1; m < 64; m <<= 1) dot += __shfl_xor(dot, m, 64);
        if (lane == 0) {
            float S = sa_s + SB[t];
            float Q = qa_s + QB[t] + 2.f * dot;
            float mean = S * (1.f / 2048.f);
            float var  = Q * (1.f / 2048.f) - mean * mean;
            float inv  = rsqrtf(var + EPSF);
            float sc   = inv * g1[p];
            statA[p] = sc;
            statB[p] = be1[p] - mean * sc;
        }
    }
}

// ---------------- Kernel C: edge MLP + aggregation ----------------
// grid 4096 blocks: b = bx>>6, g = bx&63 -> src nodes {2g, 2g+1}.
// 256 thr: s_local = tid>>7 (wave-uniform), e = tid&127 (127 valid edges).
__global__ __launch_bounds__(256) void edges_kernel(
    const float* __restrict__ AT, const float* __restrict__ BT,
    const int* __restrict__ tgt,
    const float* __restrict__ statA, const float* __restrict__ statB,
    const float* __restrict__ W2, const float* __restrict__ b2,
    const float* __restrict__ W3, const float* __restrict__ b3,
    float* __restrict__ edges_out, float* __restrict__ agg)
{
    __shared__ float aggbuf[2][32];
    int tid = threadIdx.x;
    int b = blockIdx.x >> 6;
    int g = blockIdx.x & 63;

    if (tid < 64) aggbuf[tid >> 5][tid & 31] = 0.f;
    __syncthreads();

    int s_l = __builtin_amdgcn_readfirstlane(tid >> 7);   // wave-uniform
    int s = g * 2 + s_l;
    int e = tid & 127;
    bool valid = (e < 127);
    int ec = valid ? e : 126;
    int p = s * 127 + ec;

    int t = tgt[p];
    float sc = statA[p], sh = statB[p];

    const float* arow = AT + ((size_t)s * 64 + b) * 32;   // uniform -> s_load
    const float4* b4 = (const float4*)(BT + ((size_t)t * 64 + b) * 32);

    float nh[32];
    #pragma unroll
    for (int q = 0; q < 8; ++q) {
        float4 v = b4[q];
        nh[4*q+0] = arow[4*q+0] + v.x;
        nh[4*q+1] = arow[4*q+1] + v.y;
        nh[4*q+2] = arow[4*q+2] + v.z;
        nh[4*q+3] = arow[4*q+3] + v.w;
    }
    #pragma unroll
    for (int j = 0; j < 32; ++j) {
        float x = nh[j] * sc + sh;
        nh[j] = fmaxf(x, 0.01f * x);     // leaky
    }

    float h2[32];
    #pragma unroll
    for (int j = 0; j < 32; ++j) h2[j] = b2[j];
    #pragma unroll
    for (int k = 0; k < 32; ++k) {
        float v = nh[k];
        #pragma unroll
        for (int j = 0; j < 32; ++j) h2[j] += v * W2[k * 32 + j];   // uniform W2 -> s_load
    }
    #pragma unroll
    for (int j = 0; j < 32; ++j) {
        float x = h2[j];
        h2[j] = fmaxf(x, 0.01f * x);
    }

    float o[33];
    #pragma unroll
    for (int c = 0; c < 33; ++c) o[c] = b3[c];
    #pragma unroll
    for (int k = 0; k < 32; ++k) {
        float v = h2[k];
        #pragma unroll
        for (int c = 0; c < 33; ++c) o[c] += v * W3[k * 33 + c];    // uniform W3 -> s_load
    }

    float ev = 1.f / (1.f + __expf(-o[0]));
    if (valid) {
        edges_out[(size_t)b * PP + p] = ev;
        #pragma unroll
        for (int d = 0; d < 32; ++d) {
            int dd = (d + e) & 31;                 // rotate: 2-way LDS conflict max
            atomicAdd(&aggbuf[s_l][dd], ev * o[1 + dd]);
        }
    }
    __syncthreads();
    if (tid < 64) {
        int sl = tid >> 5, d = tid & 31;
        agg[((size_t)b * 128 + g * 2 + sl) * 32 + d] = aggbuf[sl][d];
    }
}

// ---------------- Kernel 3a: f = [inputs, agg] @ Wf1 + bf1 + feature stats ----
__global__ __launch_bounds__(256) void f_kernel(
    const float* __restrict__ inputs, const float* __restrict__ agg,
    const float* __restrict__ Wf1, const float* __restrict__ bf1,
    float* __restrict__ f, float* __restrict__ fsum, float* __restrict__ fss)
{
    __shared__ float Wf1s[64][16];
    __shared__ float Xs[16][64];
    __shared__ float rsum[256], rss[256];

    int tid = threadIdx.x;
    int row0 = blockIdx.x * 16;
    for (int idx = tid; idx < 1024; idx += 256)
        Wf1s[idx >> 4][idx & 15] = Wf1[idx];
    for (int idx = tid; idx < 512; idx += 256) {
        int r = idx >> 5, d = idx & 31;
        Xs[r][d]      = inputs[(size_t)(row0 + r) * 32 + d];
        Xs[r][32 + d] = agg[(size_t)(row0 + r) * 32 + d];
    }
    __syncthreads();

    int rl = tid >> 4, j = tid & 15;
    float acc = bf1[j];
    #pragma unroll
    for (int k = 0; k < 64; ++k) acc += Xs[rl][k] * Wf1s[k][j];
    f[(size_t)(row0 + rl) * 16 + j] = acc;

    rsum[tid] = acc;
    rss[tid]  = acc * acc;
    __syncthreads();
    for (int s = 128; s >= 16; s >>= 1) {
        if (tid < s) { rsum[tid] += rsum[tid + s]; rss[tid] += rss[tid + s]; }
        __syncthreads();
    }
    if (tid < 16) {
        atomicAdd(&fsum[tid], rsum[tid]);
        atomicAdd(&fss[tid],  rss[tid]);
    }
}

// ---------------- Kernel 3b: normalize + @Wf2 -> out ----------------
__global__ __launch_bounds__(256) void out_kernel(
    const float* __restrict__ f, const float* __restrict__ fsum,
    const float* __restrict__ fss,
    const float* __restrict__ gf, const float* __restrict__ bef,
    const float* __restrict__ Wf2, const float* __restrict__ bf2,
    float* __restrict__ outp)
{
    __shared__ float Wf2s[16][32];
    __shared__ float sc[16], sh[16];
    __shared__ float fs[8][16];

    int tid = threadIdx.x;
    for (int idx = tid; idx < 512; idx += 256)
        Wf2s[idx >> 5][idx & 31] = Wf2[idx];
    if (tid < 16) {
        float mean = fsum[tid] * (1.f / 8192.f);
        float var  = fss[tid] * (1.f / 8192.f) - mean * mean;
        float inv  = rsqrtf(var + EPSF);
        float s    = inv * gf[tid];
        sc[tid] = s;
        sh[tid] = bef[tid] - mean * s;
    }
    int row0 = blockIdx.x * 8;
    if (tid < 128) {
        int r = tid >> 4, j = tid & 15;
        fs[r][j] = f[(size_t)(row0 + r) * 16 + j];
    }
    __syncthreads();

    int rl = tid >> 5, d = tid & 31;
    float acc = bf2[d];
    #pragma unroll
    for (int j = 0; j < 16; ++j) {
        float v = fs[rl][j] * sc[j] + sh[j];
        v = fmaxf(v, 0.01f * v);
        acc += v * Wf2s[j][d];
    }
    outp[(size_t)(row0 + rl) * 32 + d] = acc;
}

extern "C" void kernel_launch(void* const* d_in, const int* in_sizes, int n_in,
                              void* d_out, int out_size, void* d_ws, size_t ws_size,
                              hipStream_t stream) {
    const float* inputs = (const float*)d_in[0];
    const int*   tgt  = (const int*)d_in[2];
    const float* W1   = (const float*)d_in[3];
    const float* b1   = (const float*)d_in[4];
    const float* g1   = (const float*)d_in[5];
    const float* be1  = (const float*)d_in[6];
    const float* W2   = (const float*)d_in[7];
    const float* b2   = (const float*)d_in[8];
    const float* W3   = (const float*)d_in[9];
    const float* b3   = (const float*)d_in[10];
    const float* Wf1  = (const float*)d_in[11];
    const float* bf1  = (const float*)d_in[12];
    const float* gf   = (const float*)d_in[13];
    const float* bef  = (const float*)d_in[14];
    const float* Wf2  = (const float*)d_in[15];
    const float* bf2  = (const float*)d_in[16];

    float* ws    = (float*)d_ws;
    float* AT    = ws;                        // 262144
    float* BT    = AT + 262144;               // 262144
    float* SA    = BT + 262144;               // 128
    float* QA    = SA + 128;                  // 128
    float* SB    = QA + 128;                  // 128
    float* QB    = SB + 128;                  // 128
    float* statA = QB + 128;                  // P
    float* statB = statA + PP;                // P
    float* agg   = statB + PP;                // 262144
    float* f     = agg + 262144;              // 131072
    float* fsum  = f + 131072;                // 16
    float* fss   = fsum + 16;                 // 16

    float* edges_out = (float*)d_out;                    // B*P
    float* outp      = edges_out + (size_t)BB * PP;      // B*N*D

    hipMemsetAsync(fsum, 0, 2 * 16 * sizeof(float), stream);

    proj_kernel<<<128, 256, 0, stream>>>(inputs, W1, b1, AT, BT);
    sums_kernel<<<128, 256, 0, stream>>>(AT, BT, SA, QA, SB, QB);
    stats_kernel<<<128, 256, 0, stream>>>(AT, BT, SA, QA, SB, QB, tgt, g1, be1, statA, statB);
    edges_kernel<<<4096, 256, 0, stream>>>(AT, BT, tgt, statA, statB,
                                           W2, b2, W3, b3, edges_out, agg);
    f_kernel<<<8192 / 16, 256, 0, stream>>>(inputs, agg, Wf1, bf1, f, fsum, fss);
    out_kernel<<<8192 / 8, 256, 0, stream>>>(f, fsum, fss, gf, bef, Wf2, bf2, outp);
}

// Round 3
// 182.353 us; speedup vs baseline: 3.8239x; 2.0769x over previous
//
#include <hip/hip_runtime.h>
#include <hip/hip_bf16.h>
#include <math.h>

#define BB 64
#define NN 128
#define DD 32
#define PP (NN * (NN - 1))   // 16256
#define EPSF 1e-5f

typedef __attribute__((ext_vector_type(8))) short bf16x8;
typedef __attribute__((ext_vector_type(4))) float f32x4;

static __device__ __forceinline__ unsigned short f2bf(float x) {
    unsigned u = __builtin_bit_cast(unsigned, x);
    u += 0x7fff + ((u >> 16) & 1);          // round-to-nearest-even
    return (unsigned short)(u >> 16);
}
static __device__ __forceinline__ float leakyf(float x) {
    return fmaxf(x, 0.01f * x);
}

// ---------------- pack kernel: W2/W3 -> bf16 B-fragment layout ----------------
// B-frag (16x16x32): lane l holds B[k][n], n = l&15, k = (l>>4)*8 + j, j=0..7.
__global__ __launch_bounds__(64) void pack_kernel(
    const float* __restrict__ W2, const float* __restrict__ W3,
    unsigned short* __restrict__ W2p, unsigned short* __restrict__ W3p)
{
    int l = threadIdx.x;
    int n = l & 15, kc = l >> 4;
    #pragma unroll
    for (int ct = 0; ct < 2; ++ct)
        #pragma unroll
        for (int j = 0; j < 8; ++j) {
            int k = kc * 8 + j;
            W2p[(ct * 64 + l) * 8 + j] = f2bf(W2[k * 32 + ct * 16 + n]);
        }
    #pragma unroll
    for (int ct = 0; ct < 3; ++ct)
        #pragma unroll
        for (int j = 0; j < 8; ++j) {
            int k = kc * 8 + j;
            int c = ct * 16 + n;
            W3p[(ct * 64 + l) * 8 + j] = f2bf(c < 33 ? W3[k * 33 + c] : 0.f);
        }
}

// ---------------- Kernel A: per-node projections ----------------
__global__ __launch_bounds__(256) void proj_kernel(
    const float* __restrict__ inputs, const float* __restrict__ W1,
    const float* __restrict__ b1,
    float* __restrict__ AT, float* __restrict__ BT)
{
    __shared__ float Xs[64][32];
    int tid = threadIdx.x;
    int j = tid & 31, rblk = tid >> 5;
    int row0 = blockIdx.x * 64;

    for (int idx = tid; idx < 2048; idx += 256)
        Xs[idx >> 5][idx & 31] = inputs[(size_t)row0 * 32 + idx];

    float wa[32], wb[32];
    #pragma unroll
    for (int k = 0; k < 32; ++k) {
        wa[k] = W1[k * 32 + j];
        wb[k] = W1[(k + 32) * 32 + j];
    }
    float b1j = b1[j];
    __syncthreads();

    #pragma unroll
    for (int i = 0; i < 8; ++i) {
        int r = rblk * 8 + i;
        float a = b1j, c = 0.f;
        #pragma unroll
        for (int k = 0; k < 32; ++k) {
            a += Xs[r][k] * wa[k];
            c += Xs[r][k] * wb[k];
        }
        int row = row0 + r;
        int n = row & 127, b = row >> 7;
        AT[((size_t)n * 64 + b) * 32 + j] = a;
        BT[((size_t)n * 64 + b) * 32 + j] = c;
    }
}

// ---------------- Kernel A2: per-node sums ----------------
__global__ __launch_bounds__(256) void sums_kernel(
    const float* __restrict__ AT, const float* __restrict__ BT,
    float* __restrict__ SA, float* __restrict__ QA,
    float* __restrict__ SB, float* __restrict__ QB)
{
    __shared__ float red[4][4];
    int n = blockIdx.x, tid = threadIdx.x;
    float sa = 0.f, qa = 0.f, sb = 0.f, qb = 0.f;
    #pragma unroll
    for (int it = 0; it < 8; ++it) {
        int m = tid + it * 256;
        float a = AT[(size_t)n * 2048 + m];
        float c = BT[(size_t)n * 2048 + m];
        sa += a; qa += a * a; sb += c; qb += c * c;
    }
    #pragma unroll
    for (int off = 32; off > 0; off >>= 1) {
        sa += __shfl_down(sa, off, 64);
        qa += __shfl_down(qa, off, 64);
        sb += __shfl_down(sb, off, 64);
        qb += __shfl_down(qb, off, 64);
    }
    int w = tid >> 6;
    if ((tid & 63) == 0) { red[w][0] = sa; red[w][1] = qa; red[w][2] = sb; red[w][3] = qb; }
    __syncthreads();
    if (tid == 0) {
        SA[n] = red[0][0] + red[1][0] + red[2][0] + red[3][0];
        QA[n] = red[0][1] + red[1][1] + red[2][1] + red[3][1];
        SB[n] = red[0][2] + red[1][2] + red[2][2] + red[3][2];
        QB[n] = red[0][3] + red[1][3] + red[2][3] + red[3][3];
    }
}

// ---------------- Kernel B: per-edge LN stats via cross-dot ----------------
__global__ __launch_bounds__(256) void stats_kernel(
    const float* __restrict__ AT, const float* __restrict__ BT,
    const float* __restrict__ SA, const float* __restrict__ QA,
    const float* __restrict__ SB, const float* __restrict__ QB,
    const int* __restrict__ tgt,
    const float* __restrict__ g1, const float* __restrict__ be1,
    float* __restrict__ statA, float* __restrict__ statB)
{
    __shared__ float As[2048];
    int s = blockIdx.x, tid = threadIdx.x;
    for (int idx = tid; idx < 2048; idx += 256)
        As[idx] = AT[(size_t)s * 2048 + idx];
    __syncthreads();

    int w = tid >> 6, lane = tid & 63;
    float sa_s = SA[s], qa_s = QA[s];
    for (int e = w; e < 127; e += 4) {
        int p = s * 127 + e;
        int t = tgt[p];
        const float4* bt4 = (const float4*)(BT + (size_t)t * 2048);
        const float4* as4 = (const float4*)As;
        float dot = 0.f;
        #pragma unroll
        for (int it = 0; it < 8; ++it) {
            float4 bv = bt4[lane + it * 64];
            float4 av = as4[lane + it * 64];
            dot += av.x * bv.x + av.y * bv.y + av.z * bv.z + av.w * bv.w;
        }
        #pragma unroll
        for (int m = 1; m < 64; m <<= 1) dot += __shfl_xor(dot, m, 64);
        if (lane == 0) {
            float S = sa_s + SB[t];
            float Q = qa_s + QB[t] + 2.f * dot;
            float mean = S * (1.f / 2048.f);
            float var  = Q * (1.f / 2048.f) - mean * mean;
            float inv  = rsqrtf(var + EPSF);
            float sc   = inv * g1[p];
            statA[p] = sc;
            statB[p] = be1[p] - mean * sc;
        }
    }
}

// ---------------- Kernel C: MFMA edge MLP + aggregation ----------------
// block = (b = bx>>7, s = bx&127), 256 thr = 4 waves, 127 edge rows (+1 pad).
__global__ __launch_bounds__(256) void edges_kernel(
    const float* __restrict__ AT, const float* __restrict__ BT,
    const float* __restrict__ statA, const float* __restrict__ statB,
    const unsigned short* __restrict__ W2p, const unsigned short* __restrict__ W3p,
    const float* __restrict__ b2, const float* __restrict__ b3,
    float* __restrict__ edges_out, float* __restrict__ agg)
{
    __shared__ __align__(16) unsigned short Abuf[8][64][8];  // nh, A-frag packed
    __shared__ __align__(16) unsigned short Hbuf[8][64][8];  // h2, A-frag packed
    __shared__ __align__(16) float evb[128];
    __shared__ float aggbuf[32];

    int tid = threadIdx.x;
    int b = blockIdx.x >> 7;
    int s = blockIdx.x & 127;

    if (tid < 32) aggbuf[tid] = 0.f;

    // ---- step 1: nh = leaky(LN(A'[s,b] + Bm[t,b])) -> Abuf (bf16, A-frag order)
    int e2 = tid >> 1;          // edge row 0..127 (127 = pad)
    int half = tid & 1;         // k chunk of 16
    int k0 = half * 16;
    int m = e2 & 15, r = e2 >> 4;
    const float* arow = AT + ((size_t)s * 64 + b) * 32;

    float nh[16];
    if (e2 < 127) {
        int t = e2 + (e2 >= s);
        int p = s * 127 + e2;
        float sc = statA[p], sh = statB[p];
        const float4* brow = (const float4*)(BT + ((size_t)t * 64 + b) * 32 + k0);
        const float4* ar4  = (const float4*)(arow + k0);
        #pragma unroll
        for (int q = 0; q < 4; ++q) {
            float4 bv = brow[q];
            float4 av = ar4[q];
            nh[4*q+0] = leakyf((av.x + bv.x) * sc + sh);
            nh[4*q+1] = leakyf((av.y + bv.y) * sc + sh);
            nh[4*q+2] = leakyf((av.z + bv.z) * sc + sh);
            nh[4*q+3] = leakyf((av.w + bv.w) * sc + sh);
        }
    } else {
        #pragma unroll
        for (int q = 0; q < 16; ++q) nh[q] = 0.f;
    }
    bf16x8 v0, v1;
    #pragma unroll
    for (int j = 0; j < 8; ++j) {
        v0[j] = (short)f2bf(nh[j]);
        v1[j] = (short)f2bf(nh[8 + j]);
    }
    int L0 = 2 * half * 16 + m;     // target lane for k chunk k0..k0+7
    *(bf16x8*)&Abuf[r][L0][0]      = v0;
    *(bf16x8*)&Abuf[r][L0 + 16][0] = v1;

    // ---- per-lane B-fragments (loaded once per block) ----
    int lane = tid & 63;
    int w = tid >> 6;
    int col = lane & 15, q4 = (lane >> 4) * 4;
    bf16x8 wb2[2], wb3[3];
    wb2[0] = *(const bf16x8*)(W2p + (0 * 64 + lane) * 8);
    wb2[1] = *(const bf16x8*)(W2p + (1 * 64 + lane) * 8);
    wb3[0] = *(const bf16x8*)(W3p + (0 * 64 + lane) * 8);
    wb3[1] = *(const bf16x8*)(W3p + (1 * 64 + lane) * 8);
    wb3[2] = *(const bf16x8*)(W3p + (2 * 64 + lane) * 8);
    float b2c0 = b2[col], b2c1 = b2[16 + col];
    float b3c[3];
    #pragma unroll
    for (int ct = 0; ct < 3; ++ct) {
        int c = ct * 16 + col;
        b3c[ct] = (c < 33) ? b3[c] : 0.f;
    }
    __syncthreads();

    // ---- GEMM2: h2 = leaky(nh @ W2 + b2) -> Hbuf (A-frag order) ----
    #pragma unroll
    for (int rt = 0; rt < 2; ++rt) {
        int r2 = w * 2 + rt;
        bf16x8 a = *(const bf16x8*)&Abuf[r2][lane][0];
        f32x4 c0 = {0.f, 0.f, 0.f, 0.f}, c1 = {0.f, 0.f, 0.f, 0.f};
        c0 = __builtin_amdgcn_mfma_f32_16x16x32_bf16(a, wb2[0], c0, 0, 0, 0);
        c1 = __builtin_amdgcn_mfma_f32_16x16x32_bf16(a, wb2[1], c1, 0, 0, 0);
        #pragma unroll
        for (int reg = 0; reg < 4; ++reg) {
            float x = leakyf(c0[reg] + b2c0);
            int c = col;
            Hbuf[r2][(c >> 3) * 16 + q4 + reg][c & 7] = f2bf(x);
            float y = leakyf(c1[reg] + b2c1);
            int c2 = 16 + col;
            Hbuf[r2][(c2 >> 3) * 16 + q4 + reg][c2 & 7] = f2bf(y);
        }
    }
    __syncthreads();

    // ---- GEMM3: o = h2 @ W3 + b3 (48 padded cols) ----
    f32x4 o[2][3];
    #pragma unroll
    for (int rt = 0; rt < 2; ++rt) {
        int r2 = w * 2 + rt;
        bf16x8 a2 = *(const bf16x8*)&Hbuf[r2][lane][0];
        #pragma unroll
        for (int ct = 0; ct < 3; ++ct) {
            f32x4 cc = {0.f, 0.f, 0.f, 0.f};
            o[rt][ct] = __builtin_amdgcn_mfma_f32_16x16x32_bf16(a2, wb3[ct], cc, 0, 0, 0);
        }
    }

    // ---- sigmoid col0 -> ev (LDS) + edges_out ----
    if (col == 0) {
        #pragma unroll
        for (int rt = 0; rt < 2; ++rt) {
            int r2 = w * 2 + rt;
            int row0 = r2 * 16 + q4;
            float e0 = 1.f / (1.f + __expf(-(o[rt][0][0] + b3c[0])));
            float e1 = 1.f / (1.f + __expf(-(o[rt][0][1] + b3c[0])));
            float e2v = 1.f / (1.f + __expf(-(o[rt][0][2] + b3c[0])));
            float e3 = 1.f / (1.f + __expf(-(o[rt][0][3] + b3c[0])));
            float4 ev4;
            ev4.x = e0; ev4.y = e1; ev4.z = e2v;
            ev4.w = (row0 == 124) ? 0.f : e3;    // row 127 = pad
            *(float4*)&evb[row0] = ev4;
            float* ep = edges_out + (size_t)b * PP + s * 127 + row0;
            ep[0] = e0; ep[1] = e1; ep[2] = e2v;
            if (row0 != 124) ep[3] = e3;
        }
    }
    __syncthreads();

    // ---- agg partials: agg[d] = sum_rows ev[row] * (o[row][1+d]) ----
    #pragma unroll
    for (int ct = 0; ct < 3; ++ct) {
        int c = ct * 16 + col;
        if (c >= 1 && c <= 32) {
            float part = 0.f;
            #pragma unroll
            for (int rt = 0; rt < 2; ++rt) {
                int r2 = w * 2 + rt;
                int row0 = r2 * 16 + q4;
                float4 ev4 = *(const float4*)&evb[row0];
                float bb3 = b3c[ct];
                part += ev4.x * (o[rt][ct][0] + bb3);
                part += ev4.y * (o[rt][ct][1] + bb3);
                part += ev4.z * (o[rt][ct][2] + bb3);
                part += ev4.w * (o[rt][ct][3] + bb3);
            }
            atomicAdd(&aggbuf[c - 1], part);
        }
    }
    __syncthreads();
    if (tid < 32) agg[((size_t)b * 128 + s) * 32 + tid] = aggbuf[tid];
}

// ---------------- Kernel 3a: f = [inputs, agg] @ Wf1 + stats ----------------
__global__ __launch_bounds__(256) void f_kernel(
    const float* __restrict__ inputs, const float* __restrict__ agg,
    const float* __restrict__ Wf1, const float* __restrict__ bf1,
    float* __restrict__ f, float* __restrict__ fsum, float* __restrict__ fss)
{
    __shared__ float Wf1s[64][16];
    __shared__ float Xs[16][64];
    __shared__ float rsum[256], rss[256];

    int tid = threadIdx.x;
    int row0 = blockIdx.x * 16;
    for (int idx = tid; idx < 1024; idx += 256)
        Wf1s[idx >> 4][idx & 15] = Wf1[idx];
    for (int idx = tid; idx < 512; idx += 256) {
        int r = idx >> 5, d = idx & 31;
        Xs[r][d]      = inputs[(size_t)(row0 + r) * 32 + d];
        Xs[r][32 + d] = agg[(size_t)(row0 + r) * 32 + d];
    }
    __syncthreads();

    int rl = tid >> 4, j = tid & 15;
    float acc = bf1[j];
    #pragma unroll
    for (int k = 0; k < 64; ++k) acc += Xs[rl][k] * Wf1s[k][j];
    f[(size_t)(row0 + rl) * 16 + j] = acc;

    rsum[tid] = acc;
    rss[tid]  = acc * acc;
    __syncthreads();
    for (int s = 128; s >= 16; s >>= 1) {
        if (tid < s) { rsum[tid] += rsum[tid + s]; rss[tid] += rss[tid + s]; }
        __syncthreads();
    }
    if (tid < 16) {
        atomicAdd(&fsum[tid], rsum[tid]);
        atomicAdd(&fss[tid],  rss[tid]);
    }
}

// ---------------- Kernel 3b: normalize + @Wf2 -> out ----------------
__global__ __launch_bounds__(256) void out_kernel(
    const float* __restrict__ f, const float* __restrict__ fsum,
    const float* __restrict__ fss,
    const float* __restrict__ gf, const float* __restrict__ bef,
    const float* __restrict__ Wf2, const float* __restrict__ bf2,
    float* __restrict__ outp)
{
    __shared__ float Wf2s[16][32];
    __shared__ float sc[16], sh[16];
    __shared__ float fs[8][16];

    int tid = threadIdx.x;
    for (int idx = tid; idx < 512; idx += 256)
        Wf2s[idx >> 5][idx & 31] = Wf2[idx];
    if (tid < 16) {
        float mean = fsum[tid] * (1.f / 8192.f);
        float var  = fss[tid] * (1.f / 8192.f) - mean * mean;
        float inv  = rsqrtf(var + EPSF);
        float s    = inv * gf[tid];
        sc[tid] = s;
        sh[tid] = bef[tid] - mean * s;
    }
    int row0 = blockIdx.x * 8;
    if (tid < 128) {
        int r = tid >> 4, j = tid & 15;
        fs[r][j] = f[(size_t)(row0 + r) * 16 + j];
    }
    __syncthreads();

    int rl = tid >> 5, d = tid & 31;
    float acc = bf2[d];
    #pragma unroll
    for (int j = 0; j < 16; ++j) {
        float v = fs[rl][j] * sc[j] + sh[j];
        v = fmaxf(v, 0.01f * v);
        acc += v * Wf2s[j][d];
    }
    outp[(size_t)(row0 + rl) * 32 + d] = acc;
}

extern "C" void kernel_launch(void* const* d_in, const int* in_sizes, int n_in,
                              void* d_out, int out_size, void* d_ws, size_t ws_size,
                              hipStream_t stream) {
    const float* inputs = (const float*)d_in[0];
    const int*   tgt  = (const int*)d_in[2];
    const float* W1   = (const float*)d_in[3];
    const float* b1   = (const float*)d_in[4];
    const float* g1   = (const float*)d_in[5];
    const float* be1  = (const float*)d_in[6];
    const float* W2   = (const float*)d_in[7];
    const float* b2   = (const float*)d_in[8];
    const float* W3   = (const float*)d_in[9];
    const float* b3   = (const float*)d_in[10];
    const float* Wf1  = (const float*)d_in[11];
    const float* bf1  = (const float*)d_in[12];
    const float* gf   = (const float*)d_in[13];
    const float* bef  = (const float*)d_in[14];
    const float* Wf2  = (const float*)d_in[15];
    const float* bf2  = (const float*)d_in[16];

    float* ws    = (float*)d_ws;
    float* AT    = ws;                        // 262144
    float* BT    = AT + 262144;               // 262144
    float* SA    = BT + 262144;               // 128
    float* QA    = SA + 128;                  // 128
    float* SB    = QA + 128;                  // 128
    float* QB    = SB + 128;                  // 128
    float* statA = QB + 128;                  // 16256
    float* statB = statA + PP;                // 16256
    float* agg   = statB + PP;                // 262144
    float* f     = agg + 262144;              // 131072
    float* fsum  = f + 131072;                // 16
    float* fss   = fsum + 16;                 // 16
    unsigned short* W2p = (unsigned short*)(fss + 16);   // 1024 ushort
    unsigned short* W3p = W2p + 1024;                    // 1536 ushort

    float* edges_out = (float*)d_out;                    // B*P
    float* outp      = edges_out + (size_t)BB * PP;      // B*N*D

    hipMemsetAsync(fsum, 0, 2 * 16 * sizeof(float), stream);

    pack_kernel<<<1, 64, 0, stream>>>(W2, W3, W2p, W3p);
    proj_kernel<<<128, 256, 0, stream>>>(inputs, W1, b1, AT, BT);
    sums_kernel<<<128, 256, 0, stream>>>(AT, BT, SA, QA, SB, QB);
    stats_kernel<<<128, 256, 0, stream>>>(AT, BT, SA, QA, SB, QB, tgt, g1, be1, statA, statB);
    edges_kernel<<<BB * NN, 256, 0, stream>>>(AT, BT, statA, statB, W2p, W3p,
                                              b2, b3, edges_out, agg);
    f_kernel<<<8192 / 16, 256, 0, stream>>>(inputs, agg, Wf1, bf1, f, fsum, fss);
    out_kernel<<<8192 / 8, 256, 0, stream>>>(f, fsum, fss, gf, bef, Wf2, bf2, outp);
}

// Round 5
// 148.605 us; speedup vs baseline: 4.6923x; 1.2271x over previous
//
#include <hip/hip_runtime.h>
#include <hip/hip_bf16.h>
#include <math.h>

#define BB 64
#define NN 128
#define DD 32
#define PP (NN * (NN - 1))   // 16256
#define EPSF 1e-5f

typedef __attribute__((ext_vector_type(8))) short bf16x8;
typedef __attribute__((ext_vector_type(4))) float f32x4;

static __device__ __forceinline__ unsigned short f2bf(float x) {
    unsigned u = __builtin_bit_cast(unsigned, x);
    u += 0x7fff + ((u >> 16) & 1);          // RNE
    return (unsigned short)(u >> 16);
}
static __device__ __forceinline__ unsigned pk2bf(float a, float b) {
    return (unsigned)f2bf(a) | ((unsigned)f2bf(b) << 16);
}
static __device__ __forceinline__ float leakyf(float x) {
    return fmaxf(x, 0.01f * x);
}

// ============ Kernel 1: proj (A'/Bm fp32+bf16) + per-node sums + pack + zero ====
// grid 128 blocks (node n) x 256 thr.
__global__ __launch_bounds__(256) void proj_kernel(
    const float* __restrict__ inputs, const float* __restrict__ W1,
    const float* __restrict__ b1,
    const float* __restrict__ W2, const float* __restrict__ W3,
    float* __restrict__ AT, float* __restrict__ BT,
    unsigned short* __restrict__ ATh, unsigned short* __restrict__ BTh,
    float* __restrict__ SA, float* __restrict__ QA,
    float* __restrict__ SB, float* __restrict__ QB,
    unsigned short* __restrict__ W2p, unsigned short* __restrict__ W3p,
    float* __restrict__ fpartA, float* __restrict__ fpartB)
{
    __shared__ float Xs[64][33];
    __shared__ float W1s[64][32];
    __shared__ float red[4][4];

    int n = blockIdx.x, tid = threadIdx.x;

    for (int idx = tid; idx < 2048; idx += 256) {
        int b = idx >> 5, d = idx & 31;
        Xs[b][d] = inputs[((size_t)b << 12) + ((size_t)n << 5) + d];
        W1s[idx >> 5][idx & 31] = W1[idx];
    }
    __syncthreads();

    int j = tid & 31, rb = tid >> 5;
    float b1j = b1[j];
    float sa = 0.f, qa = 0.f, sb = 0.f, qb = 0.f;
    #pragma unroll
    for (int i = 0; i < 8; ++i) {
        int b = rb * 8 + i;
        float a = b1j, c = 0.f;
        #pragma unroll
        for (int k = 0; k < 32; ++k) {
            a += Xs[b][k] * W1s[k][j];
            c += Xs[b][k] * W1s[32 + k][j];
        }
        size_t off = ((size_t)n * 64 + b) * 32 + j;
        AT[off] = a;  BT[off] = c;
        ATh[off] = f2bf(a);  BTh[off] = f2bf(c);
        sa += a; qa += a * a; sb += c; qb += c * c;
    }
    #pragma unroll
    for (int off = 32; off > 0; off >>= 1) {
        sa += __shfl_down(sa, off, 64);
        qa += __shfl_down(qa, off, 64);
        sb += __shfl_down(sb, off, 64);
        qb += __shfl_down(qb, off, 64);
    }
    int w = tid >> 6;
    if ((tid & 63) == 0) { red[w][0] = sa; red[w][1] = qa; red[w][2] = sb; red[w][3] = qb; }
    __syncthreads();
    if (tid == 0) {
        SA[n] = red[0][0] + red[1][0] + red[2][0] + red[3][0];
        QA[n] = red[0][1] + red[1][1] + red[2][1] + red[3][1];
        SB[n] = red[0][2] + red[1][2] + red[2][2] + red[3][2];
        QB[n] = red[0][3] + red[1][3] + red[2][3] + red[3][3];
    }

    // block 0: pack W2/W3 into B-fragment layout (bf16)
    if (blockIdx.x == 0 && tid < 64) {
        int l = tid, nn2 = l & 15, kc = l >> 4;
        #pragma unroll
        for (int ct = 0; ct < 2; ++ct)
            #pragma unroll
            for (int jj = 0; jj < 8; ++jj) {
                int k = kc * 8 + jj;
                W2p[(ct * 64 + l) * 8 + jj] = f2bf(W2[k * 32 + ct * 16 + nn2]);
            }
        #pragma unroll
        for (int ct = 0; ct < 3; ++ct)
            #pragma unroll
            for (int jj = 0; jj < 8; ++jj) {
                int k = kc * 8 + jj;
                int c = ct * 16 + nn2;
                W3p[(ct * 64 + l) * 8 + jj] = f2bf(c < 33 ? W3[k * 33 + c] : 0.f);
            }
    }
    // block 1: zero the f-stat partial buckets
    if (blockIdx.x == 1) {
        for (int idx = tid; idx < 1024; idx += 256) {
            fpartA[idx] = 0.f;
            fpartB[idx] = 0.f;
        }
    }
}

// ============ Kernel 2: per-edge LN stats via bf16 MFMA cross-GEMM ============
// grid 64 blocks: s-tile 16 x t-tile 16. 4 waves split K=2048 into 512 each.
__global__ __launch_bounds__(256) void stats2_kernel(
    const unsigned short* __restrict__ ATh, const unsigned short* __restrict__ BTh,
    const float* __restrict__ SA, const float* __restrict__ QA,
    const float* __restrict__ SB, const float* __restrict__ QB,
    const float* __restrict__ g1, const float* __restrict__ be1,
    float* __restrict__ statA, float* __restrict__ statB)
{
    __shared__ __align__(16) float part[4][64][4];
    int tid = threadIdx.x;
    int lane = tid & 63, w = tid >> 6;
    int s0 = (blockIdx.x >> 3) * 16, t0 = (blockIdx.x & 7) * 16;

    int m = lane & 15, kc = lane >> 4;
    const unsigned short* abase = ATh + (size_t)(s0 + m) * 2048 + kc * 8 + w * 512;
    const unsigned short* bbase = BTh + (size_t)(t0 + m) * 2048 + kc * 8 + w * 512;

    f32x4 acc = {0.f, 0.f, 0.f, 0.f};
    #pragma unroll
    for (int step = 0; step < 16; ++step) {
        bf16x8 av = *(const bf16x8*)(abase + step * 32);
        bf16x8 bv = *(const bf16x8*)(bbase + step * 32);
        acc = __builtin_amdgcn_mfma_f32_16x16x32_bf16(av, bv, acc, 0, 0, 0);
    }
    *(f32x4*)&part[w][lane][0] = acc;
    __syncthreads();

    if (w == 0) {
        #pragma unroll
        for (int ww = 1; ww < 4; ++ww) {
            f32x4 o = *(const f32x4*)&part[ww][lane][0];
            acc[0] += o[0]; acc[1] += o[1]; acc[2] += o[2]; acc[3] += o[3];
        }
        int col = lane & 15, quad = lane >> 4;
        int t = t0 + col;
        float sbt = SB[t], qbt = QB[t];
        #pragma unroll
        for (int r = 0; r < 4; ++r) {
            int s = s0 + quad * 4 + r;
            if (s != t) {
                int e = t - (t > s);
                int p = s * 127 + e;
                float S = SA[s] + sbt;
                float Q = QA[s] + qbt + 2.f * acc[r];
                float mean = S * (1.f / 2048.f);
                float var  = Q * (1.f / 2048.f) - mean * mean;
                float inv  = rsqrtf(var + EPSF);
                float sc   = inv * g1[p];
                statA[p] = sc;
                statB[p] = be1[p] - mean * sc;
            }
        }
    }
}

// ============ Kernel 3: MFMA edge MLP + aggregation + f-row tail ============
// block = (b = bx>>7, s = bx&127), 256 thr.
__global__ __launch_bounds__(256) void edges_kernel(
    const float* __restrict__ AT, const float* __restrict__ BT,
    const float* __restrict__ statA, const float* __restrict__ statB,
    const unsigned short* __restrict__ W2p, const unsigned short* __restrict__ W3p,
    const float* __restrict__ b2, const float* __restrict__ b3,
    const float* __restrict__ inputs, const float* __restrict__ Wf1,
    const float* __restrict__ bf1,
    float* __restrict__ edges_out, float* __restrict__ agg,
    float* __restrict__ f, float* __restrict__ fpartA, float* __restrict__ fpartB)
{
    __shared__ __align__(16) unsigned short Abuf[8][64][8];
    __shared__ __align__(16) unsigned short Hbuf[8][64][8];
    __shared__ __align__(16) float evb[128];
    __shared__ float aggbuf[32];

    int tid = threadIdx.x;
    int b = blockIdx.x >> 7;
    int s = blockIdx.x & 127;

    if (tid < 32) aggbuf[tid] = 0.f;

    // ---- nh = leaky(LN(A'[s,b] + Bm[t,b])) -> Abuf (bf16, A-frag order)
    int e2 = tid >> 1;
    int half = tid & 1;
    int k0 = half * 16;
    int m = e2 & 15, r = e2 >> 4;
    const float* arow = AT + ((size_t)s * 64 + b) * 32;

    float nh[16];
    if (e2 < 127) {
        int t = e2 + (e2 >= s);
        int p = s * 127 + e2;
        float sc = statA[p], sh = statB[p];
        const float4* brow = (const float4*)(BT + ((size_t)t * 64 + b) * 32 + k0);
        const float4* ar4  = (const float4*)(arow + k0);
        #pragma unroll
        for (int q = 0; q < 4; ++q) {
            float4 bv = brow[q];
            float4 av = ar4[q];
            nh[4*q+0] = leakyf((av.x + bv.x) * sc + sh);
            nh[4*q+1] = leakyf((av.y + bv.y) * sc + sh);
            nh[4*q+2] = leakyf((av.z + bv.z) * sc + sh);
            nh[4*q+3] = leakyf((av.w + bv.w) * sc + sh);
        }
    } else {
        #pragma unroll
        for (int q = 0; q < 16; ++q) nh[q] = 0.f;
    }
    union { bf16x8 v; unsigned u[4]; } U0, U1;
    #pragma unroll
    for (int q = 0; q < 4; ++q) {
        U0.u[q] = pk2bf(nh[2*q], nh[2*q+1]);
        U1.u[q] = pk2bf(nh[8+2*q], nh[8+2*q+1]);
    }
    int L0 = 2 * half * 16 + m;
    *(bf16x8*)&Abuf[r][L0][0]      = U0.v;
    *(bf16x8*)&Abuf[r][L0 + 16][0] = U1.v;

    // ---- B fragments ----
    int lane = tid & 63;
    int w = tid >> 6;
    int col = lane & 15, q4 = (lane >> 4) * 4;
    bf16x8 wb2[2], wb3[3];
    wb2[0] = *(const bf16x8*)(W2p + (0 * 64 + lane) * 8);
    wb2[1] = *(const bf16x8*)(W2p + (1 * 64 + lane) * 8);
    wb3[0] = *(const bf16x8*)(W3p + (0 * 64 + lane) * 8);
    wb3[1] = *(const bf16x8*)(W3p + (1 * 64 + lane) * 8);
    wb3[2] = *(const bf16x8*)(W3p + (2 * 64 + lane) * 8);
    float b2c0 = b2[col], b2c1 = b2[16 + col];
    float b3c[3];
    #pragma unroll
    for (int ct = 0; ct < 3; ++ct) {
        int c = ct * 16 + col;
        b3c[ct] = (c < 33) ? b3[c] : 0.f;
    }
    __syncthreads();

    // ---- GEMM2 ----
    #pragma unroll
    for (int rt = 0; rt < 2; ++rt) {
        int r2 = w * 2 + rt;
        bf16x8 a = *(const bf16x8*)&Abuf[r2][lane][0];
        f32x4 c0 = {0.f, 0.f, 0.f, 0.f}, c1 = {0.f, 0.f, 0.f, 0.f};
        c0 = __builtin_amdgcn_mfma_f32_16x16x32_bf16(a, wb2[0], c0, 0, 0, 0);
        c1 = __builtin_amdgcn_mfma_f32_16x16x32_bf16(a, wb2[1], c1, 0, 0, 0);
        #pragma unroll
        for (int reg = 0; reg < 4; ++reg) {
            float x = leakyf(c0[reg] + b2c0);
            int c = col;
            Hbuf[r2][(c >> 3) * 16 + q4 + reg][c & 7] = f2bf(x);
            float y = leakyf(c1[reg] + b2c1);
            int c2 = 16 + col;
            Hbuf[r2][(c2 >> 3) * 16 + q4 + reg][c2 & 7] = f2bf(y);
        }
    }
    __syncthreads();

    // ---- GEMM3 ----
    f32x4 o[2][3];
    #pragma unroll
    for (int rt = 0; rt < 2; ++rt) {
        int r2 = w * 2 + rt;
        bf16x8 a2 = *(const bf16x8*)&Hbuf[r2][lane][0];
        #pragma unroll
        for (int ct = 0; ct < 3; ++ct) {
            f32x4 cc = {0.f, 0.f, 0.f, 0.f};
            o[rt][ct] = __builtin_amdgcn_mfma_f32_16x16x32_bf16(a2, wb3[ct], cc, 0, 0, 0);
        }
    }

    // ---- sigmoid col0 -> ev + edges_out ----
    if (col == 0) {
        #pragma unroll
        for (int rt = 0; rt < 2; ++rt) {
            int r2 = w * 2 + rt;
            int row0 = r2 * 16 + q4;
            float e0 = 1.f / (1.f + __expf(-(o[rt][0][0] + b3c[0])));
            float e1 = 1.f / (1.f + __expf(-(o[rt][0][1] + b3c[0])));
            float e2v = 1.f / (1.f + __expf(-(o[rt][0][2] + b3c[0])));
            float e3 = 1.f / (1.f + __expf(-(o[rt][0][3] + b3c[0])));
            float4 ev4;
            ev4.x = e0; ev4.y = e1; ev4.z = e2v;
            ev4.w = (row0 == 124) ? 0.f : e3;
            *(float4*)&evb[row0] = ev4;
            float* ep = edges_out + (size_t)b * PP + s * 127 + row0;
            ep[0] = e0; ep[1] = e1; ep[2] = e2v;
            if (row0 != 124) ep[3] = e3;
        }
    }
    __syncthreads();

    // ---- agg partials ----
    #pragma unroll
    for (int ct = 0; ct < 3; ++ct) {
        int c = ct * 16 + col;
        if (c >= 1 && c <= 32) {
            float part = 0.f;
            #pragma unroll
            for (int rt = 0; rt < 2; ++rt) {
                int row0 = (w * 2 + rt) * 16 + q4;
                float4 ev4 = *(const float4*)&evb[row0];
                float bb3 = b3c[ct];
                part += ev4.x * (o[rt][ct][0] + bb3);
                part += ev4.y * (o[rt][ct][1] + bb3);
                part += ev4.z * (o[rt][ct][2] + bb3);
                part += ev4.w * (o[rt][ct][3] + bb3);
            }
            atomicAdd(&aggbuf[c - 1], part);
        }
    }
    __syncthreads();

    size_t row = (size_t)b * 128 + s;
    if (tid < 32) agg[row * 32 + tid] = aggbuf[tid];

    // ---- f-row tail: f[row] = [x(row), agg(row)] @ Wf1 + bf1 ----
    if (tid < 16) {
        const float* xrow = inputs + row * 32;
        float acc = bf1[tid];
        #pragma unroll
        for (int k = 0; k < 32; ++k) acc += xrow[k] * Wf1[k * 16 + tid];
        #pragma unroll
        for (int k = 0; k < 32; ++k) acc += aggbuf[k] * Wf1[(32 + k) * 16 + tid];
        f[row * 16 + tid] = acc;
        int bucket = blockIdx.x & 63;
        atomicAdd(&fpartA[bucket * 16 + tid], acc);
        atomicAdd(&fpartB[bucket * 16 + tid], acc * acc);
    }
}

// ============ Kernel 4: f-stats reduce (redundant per block) + out ============
__global__ __launch_bounds__(256) void out_kernel(
    const float* __restrict__ f,
    const float* __restrict__ fpartA, const float* __restrict__ fpartB,
    const float* __restrict__ gf, const float* __restrict__ bef,
    const float* __restrict__ Wf2, const float* __restrict__ bf2,
    float* __restrict__ outp)
{
    __shared__ float Wf2s[16][32];
    __shared__ float sc[16], sh[16];
    __shared__ float fs[8][16];

    int tid = threadIdx.x;
    for (int idx = tid; idx < 512; idx += 256)
        Wf2s[idx >> 5][idx & 31] = Wf2[idx];
    if (tid < 16) {
        float S = 0.f, Q = 0.f;
        #pragma unroll
        for (int g = 0; g < 64; ++g) {
            S += fpartA[g * 16 + tid];
            Q += fpartB[g * 16 + tid];
        }
        float mean = S * (1.f / 8192.f);
        float var  = Q * (1.f / 8192.f) - mean * mean;
        float inv  = rsqrtf(var + EPSF);
        float s    = inv * gf[tid];
        sc[tid] = s;
        sh[tid] = bef[tid] - mean * s;
    }
    int row0 = blockIdx.x * 8;
    if (tid < 128) {
        int r = tid >> 4, j = tid & 15;
        fs[r][j] = f[(size_t)(row0 + r) * 16 + j];
    }
    __syncthreads();

    int rl = tid >> 5, d = tid & 31;
    float acc = bf2[d];
    #pragma unroll
    for (int j = 0; j < 16; ++j) {
        float v = fs[rl][j] * sc[j] + sh[j];
        v = fmaxf(v, 0.01f * v);
        acc += v * Wf2s[j][d];
    }
    outp[(size_t)(row0 + rl) * 32 + d] = acc;
}

extern "C" void kernel_launch(void* const* d_in, const int* in_sizes, int n_in,
                              void* d_out, int out_size, void* d_ws, size_t ws_size,
                              hipStream_t stream) {
    const float* inputs = (const float*)d_in[0];
    const float* W1   = (const float*)d_in[3];
    const float* b1   = (const float*)d_in[4];
    const float* g1   = (const float*)d_in[5];
    const float* be1  = (const float*)d_in[6];
    const float* W2   = (const float*)d_in[7];
    const float* b2   = (const float*)d_in[8];
    const float* W3   = (const float*)d_in[9];
    const float* b3   = (const float*)d_in[10];
    const float* Wf1  = (const float*)d_in[11];
    const float* bf1  = (const float*)d_in[12];
    const float* gf   = (const float*)d_in[13];
    const float* bef  = (const float*)d_in[14];
    const float* Wf2  = (const float*)d_in[15];
    const float* bf2  = (const float*)d_in[16];

    float* ws    = (float*)d_ws;
    float* AT    = ws;                        // 262144
    float* BT    = AT + 262144;               // 262144
    float* SA    = BT + 262144;               // 128
    float* QA    = SA + 128;
    float* SB    = QA + 128;
    float* QB    = SB + 128;
    float* statA = QB + 128;                  // 16256
    float* statB = statA + PP;                // 16256
    float* region = statB + PP;               // union region: 393216 floats
    unsigned short* ATh = (unsigned short*)region;       // 262144 ush (=131072 f)
    unsigned short* BTh = ATh + 262144;                  // 262144 ush
    float* agg = region;                                 // 262144 f (aliases ATh+BTh; safe: stream-ordered)
    float* f   = region + 262144;                        // 131072 f
    float* fpartA = region + 393216;          // 1024
    float* fpartB = fpartA + 1024;            // 1024
    unsigned short* W2p = (unsigned short*)(fpartB + 1024);  // 1024 ush
    unsigned short* W3p = W2p + 1024;                        // 1536 ush

    float* edges_out = (float*)d_out;                    // B*P
    float* outp      = edges_out + (size_t)BB * PP;      // B*N*D

    proj_kernel<<<128, 256, 0, stream>>>(inputs, W1, b1, W2, W3,
                                         AT, BT, ATh, BTh, SA, QA, SB, QB,
                                         W2p, W3p, fpartA, fpartB);
    stats2_kernel<<<64, 256, 0, stream>>>(ATh, BTh, SA, QA, SB, QB,
                                          g1, be1, statA, statB);
    edges_kernel<<<BB * NN, 256, 0, stream>>>(AT, BT, statA, statB, W2p, W3p,
                                              b2, b3, inputs, Wf1, bf1,
                                              edges_out, agg, f, fpartA, fpartB);
    out_kernel<<<8192 / 8, 256, 0, stream>>>(f, fpartA, fpartB, gf, bef, Wf2, bf2, outp);
}